// Round 1
// baseline (175.125 us; speedup 1.0000x reference)
//
#include <hip/hip_runtime.h>
#include <math.h>

// Problem constants (fixed by setup_inputs): B=8, H=W=64, N=128
#define BB 8
#define HH 64
#define WW 64
#define NN 128
#define CC (HH*WW)   // 4096

__device__ __forceinline__ float sqf(float x){ return x*x; }

// One block per (dir, b, n).  dir=0: img1->img2 (coalesced rows).
// dir=1: img2->img1 (strided 2x2 gathers into the transposed volume).
// Writes partial[dir*1024 + b*128 + n] = sum_c (pred - tgt)^2 for that point.
__global__ __launch_bounds__(256) void lpml_main(
    const float* __restrict__ corr, const float* __restrict__ kp,
    float* __restrict__ partial)
{
  const int tid  = threadIdx.x;
  const int bidx = blockIdx.x;
  const int dir  = bidx >> 10;
  const int b    = (bidx >> 7) & 7;
  const int n    = bidx & 127;

  __shared__ float red[256];

  // kp layout (B,N,2,2): kp[b,n,comp,which]; which=0 -> pts1, which=1 -> pts2
  const float* kpp = kp + (size_t)(b*NN + n)*4;
  const float p1y = kpp[0], p2y = kpp[1], p1x = kpp[2], p2x = kpp[3];

  // sample point (bilinear pred) and target point (prob map)
  const float sy = dir ? p2y : p1y;
  const float sx = dir ? p2x : p1x;
  const float ty = dir ? p1y : p2y;
  const float tx = dir ? p1x : p2x;

  // ---- bilinear weights at the sample point (matches _interp_rows) ----
  const float y0f = floorf(sy), x0f = floorf(sx);
  const float wy = sy - y0f, wx = sx - x0f;
  int Y0 = (int)y0f; Y0 = Y0 < 0 ? 0 : (Y0 > HH-1 ? HH-1 : Y0);
  int X0 = (int)x0f; X0 = X0 < 0 ? 0 : (X0 > WW-1 ? WW-1 : X0);
  const int Y1 = (Y0+1 > HH-1) ? HH-1 : Y0+1;
  const int X1 = (X0+1 > WW-1) ? WW-1 : X0+1;
  const float w00 = (1.f-wy)*(1.f-wx), w01 = (1.f-wy)*wx;
  const float w10 = wy*(1.f-wx),       w11 = wy*wx;

  const size_t bbase = (size_t)b * HH * WW * CC;

  // dir==0: four contiguous channel rows (image-1 spatial neighbors)
  const float* r00 = corr + bbase + (size_t)(Y0*WW + X0) * CC;
  const float* r01 = corr + bbase + (size_t)(Y0*WW + X1) * CC;
  const float* r10 = corr + bbase + (size_t)(Y1*WW + X0) * CC;
  const float* r11 = corr + bbase + (size_t)(Y1*WW + X1) * CC;
  // dir==1: 2x2 patch offsets into each 16KB slab (image-2 coords)
  const int o00 = Y0*WW + X0, o01 = Y0*WW + X1;
  const int o10 = Y1*WW + X0, o11 = Y1*WW + X1;

  // ---- S = sum_c pred^2 over all 4096 channels ----
  float ss = 0.f;
  if (dir == 0) {
    for (int c0 = tid*4; c0 < CC; c0 += 1024) {
      const float4 a  = *(const float4*)(r00 + c0);
      const float4 bq = *(const float4*)(r01 + c0);
      const float4 cq = *(const float4*)(r10 + c0);
      const float4 dq = *(const float4*)(r11 + c0);
      const float p0 = w00*a.x + w01*bq.x + w10*cq.x + w11*dq.x;
      const float p1 = w00*a.y + w01*bq.y + w10*cq.y + w11*dq.y;
      const float p2 = w00*a.z + w01*bq.z + w10*cq.z + w11*dq.z;
      const float p3 = w00*a.w + w01*bq.w + w10*cq.w + w11*dq.w;
      ss += p0*p0 + p1*p1 + p2*p2 + p3*p3;
    }
  } else {
    const float* slabbase = corr + bbase;
    for (int cp = tid; cp < CC; cp += 256) {
      const float* slab = slabbase + (size_t)cp * CC;
      const float v = w00*slab[o00] + w01*slab[o01]
                    + w10*slab[o10] + w11*slab[o11];
      ss += v*v;
    }
  }
  red[tid] = ss; __syncthreads();
  for (int s = 128; s > 0; s >>= 1) { if (tid < s) red[tid] += red[tid+s]; __syncthreads(); }
  const float S = red[0]; __syncthreads();

  // ---- target patch: 4 scatter bins convolved with 5x5 gaussian -> 6x6 ----
  // gaussian 1D kernel: sigma = 2/3, exp(-d^2 * 9/8), normalized
  float k1d[5];
  {
    float ksum = 0.f;
#pragma unroll
    for (int i = 0; i < 5; ++i) { const float d = (float)(i-2); k1d[i] = expf(-d*d*1.125f); ksum += k1d[i]; }
#pragma unroll
    for (int i = 0; i < 5; ++i) k1d[i] /= ksum;
  }

  const float fy = floorf(ty), cy = ceilf(ty);
  const float fx = floorf(tx), cx = ceilf(tx);
  // torch.pairwise_distance adds eps=1e-6 to the difference (per component)
  const float d0 = sqrtf(sqf(fy-ty+1e-6f) + sqf(fx-tx+1e-6f));
  const float d1 = sqrtf(sqf(fy-ty+1e-6f) + sqf(cx-tx+1e-6f));
  const float d2 = sqrtf(sqf(cy-ty+1e-6f) + sqf(fx-tx+1e-6f));
  const float d3 = sqrtf(sqf(cy-ty+1e-6f) + sqf(cx-tx+1e-6f));
  const float sd = fmaxf(d0+d1+d2+d3, 1e-12f);
  const float t0 = d0/sd, t1 = d1/sd, t2 = d2/sd, t3 = d3/sd;
  const int ify = (int)fy, ifx = (int)fx;
  const int ddy = (int)cy - ify, ddx = (int)cx - ifx; // 0 or 1 (0 if coord integral)
  // accumulate the 4 scatter weights into the 2x2 local cell (handles dup bins)
  const float loc00 = t0 + (ddx==0?t1:0.f) + (ddy==0?t2:0.f) + ((ddy==0&&ddx==0)?t3:0.f);
  const float loc01 = (ddx==1?t1:0.f) + ((ddy==0&&ddx==1)?t3:0.f);
  const float loc10 = (ddy==1?t2:0.f) + ((ddy==1&&ddx==0)?t3:0.f);
  const float loc11 = ((ddy==1&&ddx==1)?t3:0.f);

  // each of threads 0..35 owns one bin of the 6x6 conv output window
  float val = 0.f;
  int by = 0, bx = 0;
  bool inb = false;
  if (tid < 36) {
    const int r = tid / 6, c = tid % 6;
    by = ify - 2 + r; bx = ifx - 2 + c;
    inb = (by >= 0 && by < HH && bx >= 0 && bx < WW);
    if (inb) {
      const float kr0 = (r <= 4) ? k1d[r]   : 0.f;  // dr=0 row factor
      const float kr1 = (r >= 1) ? k1d[r-1] : 0.f;  // dr=1 row factor
      const float kc0 = (c <= 4) ? k1d[c]   : 0.f;
      const float kc1 = (c >= 1) ? k1d[c-1] : 0.f;
      val = loc00*kr0*kc0 + loc01*kr0*kc1 + loc10*kr1*kc0 + loc11*kr1*kc1;
    }
  }

  // norm^2 of the target map (zeros outside the 36-bin window)
  red[tid] = inb ? val*val : 0.f; __syncthreads();
  for (int s = 128; s > 0; s >>= 1) { if (tid < s) red[tid] += red[tid+s]; __syncthreads(); }
  const float nrm2 = red[0]; __syncthreads();
  const float nrmc = fmaxf(sqrtf(nrm2), 1e-12f);
  const float tgtsq = nrm2 / (nrmc*nrmc);  // sum_c tgt^2 (==1 normally)

  // D = sum_c tgt*pred over the 36 nonzero bins
  float dc = 0.f;
  if (tid < 36 && inb) {
    float predbin;
    if (dir == 0) {
      const int cbin = by*WW + bx;   // channel = image-2 flat coord
      predbin = w00*r00[cbin] + w01*r01[cbin] + w10*r10[cbin] + w11*r11[cbin];
    } else {
      const float* slab = corr + bbase + (size_t)(by*WW + bx) * CC; // (y1,x1) bin
      predbin = w00*slab[o00] + w01*slab[o01] + w10*slab[o10] + w11*slab[o11];
    }
    dc = (val / nrmc) * predbin;
  }
  red[tid] = dc; __syncthreads();
  for (int s = 128; s > 0; s >>= 1) { if (tid < s) red[tid] += red[tid+s]; __syncthreads(); }

  if (tid == 0) partial[bidx] = S - 2.f*red[0] + tgtsq;
}

// Final reduce: per (dir,b) sum over n -> sqrt -> mean over b -> add dirs.
__global__ void lpml_reduce(const float* __restrict__ partial, float* __restrict__ out)
{
  __shared__ float sh[16];
  const int tid = threadIdx.x;
  if (tid < 16) {
    const int dir = tid >> 3, b = tid & 7;
    const float* p = partial + dir*(BB*NN) + b*NN;
    float s = 0.f;
    for (int i = 0; i < NN; ++i) s += p[i];
    sh[tid] = sqrtf(s);
  }
  __syncthreads();
  if (tid == 0) {
    float l1 = 0.f, l2 = 0.f;
    for (int i = 0; i < BB; ++i) { l1 += sh[i]; l2 += sh[8+i]; }
    out[0] = l1/(float)BB + l2/(float)BB;
  }
}

extern "C" void kernel_launch(void* const* d_in, const int* in_sizes, int n_in,
                              void* d_out, int out_size, void* d_ws, size_t ws_size,
                              hipStream_t stream) {
  const float* corr = (const float*)d_in[0];  // (B,H,W,H,W) f32
  const float* kp   = (const float*)d_in[1];  // (B,N,2,2) f32
  float* partial = (float*)d_ws;              // 2*B*N floats = 8KB
  hipLaunchKernelGGL(lpml_main, dim3(2*BB*NN), dim3(256), 0, stream,
                     corr, kp, partial);
  hipLaunchKernelGGL(lpml_reduce, dim3(1), dim3(64), 0, stream,
                     partial, (float*)d_out);
}

// Round 2
// 117.242 us; speedup vs baseline: 1.4937x; 1.4937x over previous
//
#include <hip/hip_runtime.h>
#include <math.h>

// Problem constants (fixed by setup_inputs): B=8, H=W=64, N=128
#define BB 8
#define HH 64
#define WW 64
#define NN 128
#define CC (HH*WW)   // 4096

__device__ __forceinline__ float sqf(float x){ return x*x; }

// ws layout (floats): [0,2048) partial per (dir,b,n); [2048,3072) acc21 per (b,n)

__global__ void lpml_zero(float* __restrict__ acc21)
{
  const int i = threadIdx.x + blockIdx.x * 256;
  if (i < BB*NN) acc21[i] = 0.f;
}

// Streaming dir-1 S: one block per (b, y1, xhalf). Streams 32 planes
// corr[b,y1,x1,:,:] (16KB each) coalesced into LDS, 2 per iteration; the 128
// points of batch b gather their 2x2 bilinear taps from LDS and accumulate
// v^2. One atomicAdd per (block,point) into acc21[b*NN+n].
__global__ __launch_bounds__(256) void lpml_stream21(
    const float* __restrict__ corr, const float* __restrict__ kp,
    float* __restrict__ acc21)
{
  const int bidx = blockIdx.x;
  const int half = bidx & 1;
  const int y1   = (bidx >> 1) & (HH-1);
  const int b    = bidx >> 7;
  const int tid  = threadIdx.x;

  __shared__ float plane[2][CC];     // 32 KB
  __shared__ int   soff[NN][4];
  __shared__ float swt[NN][4];
  __shared__ float red[256];

  if (tid < NN) {
    // kp layout (B,N,2,2): [b][n][comp][which]; which=1 -> pts2
    const float* kpp = kp + (size_t)(b*NN + tid)*4;
    const float sy = kpp[1], sx = kpp[3];
    const float y0f = floorf(sy), x0f = floorf(sx);
    const float wy = sy - y0f, wx = sx - x0f;
    int Y0 = (int)y0f; Y0 = Y0 < 0 ? 0 : (Y0 > HH-1 ? HH-1 : Y0);
    int X0 = (int)x0f; X0 = X0 < 0 ? 0 : (X0 > WW-1 ? WW-1 : X0);
    const int Y1 = (Y0+1 > HH-1) ? HH-1 : Y0+1;
    const int X1 = (X0+1 > WW-1) ? WW-1 : X0+1;
    soff[tid][0] = Y0*WW + X0; soff[tid][1] = Y0*WW + X1;
    soff[tid][2] = Y1*WW + X0; soff[tid][3] = Y1*WW + X1;
    swt[tid][0] = (1.f-wy)*(1.f-wx); swt[tid][1] = (1.f-wy)*wx;
    swt[tid][2] = wy*(1.f-wx);       swt[tid][3] = wy*wx;
  }
  __syncthreads();

  const int n = tid & (NN-1);
  const int g = tid >> 7;            // which plane of the loaded pair
  const int o00 = soff[n][0], o01 = soff[n][1], o10 = soff[n][2], o11 = soff[n][3];
  const float w00 = swt[n][0], w01 = swt[n][1], w10 = swt[n][2], w11 = swt[n][3];

  const size_t rowbase = (((size_t)b*HH + y1)*WW + (size_t)half*32) * CC;
  float accv = 0.f;
  for (int it = 0; it < 16; ++it) {
    const float4* src = (const float4*)(corr + rowbase + (size_t)(2*it)*CC);
    float4* dst = (float4*)(&plane[0][0]);
#pragma unroll
    for (int k = 0; k < 8; ++k) dst[tid + 256*k] = src[tid + 256*k];
    __syncthreads();
    const float* P = &plane[g][0];
    const float v = w00*P[o00] + w01*P[o01] + w10*P[o10] + w11*P[o11];
    accv += v*v;
    __syncthreads();
  }

  red[tid] = accv; __syncthreads();
  if (tid < NN) atomicAdd(&acc21[b*NN + n], red[tid] + red[tid+NN]);
}

// Per-point kernel: one block per (dir,b,n). dir=0 computes full S (coalesced
// rows); dir=1's S comes from lpml_stream21. Both dirs compute target window,
// its norm, and the cross term D here.
__global__ __launch_bounds__(256) void lpml_main(
    const float* __restrict__ corr, const float* __restrict__ kp,
    float* __restrict__ partial)
{
  const int tid  = threadIdx.x;
  const int bidx = blockIdx.x;
  const int dir  = bidx >> 10;
  const int b    = (bidx >> 7) & 7;
  const int n    = bidx & 127;

  __shared__ float red[256];

  const float* kpp = kp + (size_t)(b*NN + n)*4;
  const float p1y = kpp[0], p2y = kpp[1], p1x = kpp[2], p2x = kpp[3];

  const float sy = dir ? p2y : p1y;
  const float sx = dir ? p2x : p1x;
  const float ty = dir ? p1y : p2y;
  const float tx = dir ? p1x : p2x;

  // bilinear weights at the sample point (matches _interp_rows)
  const float y0f = floorf(sy), x0f = floorf(sx);
  const float wy = sy - y0f, wx = sx - x0f;
  int Y0 = (int)y0f; Y0 = Y0 < 0 ? 0 : (Y0 > HH-1 ? HH-1 : Y0);
  int X0 = (int)x0f; X0 = X0 < 0 ? 0 : (X0 > WW-1 ? WW-1 : X0);
  const int Y1 = (Y0+1 > HH-1) ? HH-1 : Y0+1;
  const int X1 = (X0+1 > WW-1) ? WW-1 : X0+1;
  const float w00 = (1.f-wy)*(1.f-wx), w01 = (1.f-wy)*wx;
  const float w10 = wy*(1.f-wx),       w11 = wy*wx;

  const size_t bbase = (size_t)b * HH * WW * CC;

  const float* r00 = corr + bbase + (size_t)(Y0*WW + X0) * CC;
  const float* r01 = corr + bbase + (size_t)(Y0*WW + X1) * CC;
  const float* r10 = corr + bbase + (size_t)(Y1*WW + X0) * CC;
  const float* r11 = corr + bbase + (size_t)(Y1*WW + X1) * CC;
  const int o00 = Y0*WW + X0, o01 = Y0*WW + X1;
  const int o10 = Y1*WW + X0, o11 = Y1*WW + X1;

  // ---- S = sum_c pred^2 (dir 0 only; dir 1 handled by lpml_stream21) ----
  float ss = 0.f;
  if (dir == 0) {
    for (int c0 = tid*4; c0 < CC; c0 += 1024) {
      const float4 a  = *(const float4*)(r00 + c0);
      const float4 bq = *(const float4*)(r01 + c0);
      const float4 cq = *(const float4*)(r10 + c0);
      const float4 dq = *(const float4*)(r11 + c0);
      const float p0 = w00*a.x + w01*bq.x + w10*cq.x + w11*dq.x;
      const float p1 = w00*a.y + w01*bq.y + w10*cq.y + w11*dq.y;
      const float p2 = w00*a.z + w01*bq.z + w10*cq.z + w11*dq.z;
      const float p3 = w00*a.w + w01*bq.w + w10*cq.w + w11*dq.w;
      ss += p0*p0 + p1*p1 + p2*p2 + p3*p3;
    }
  }
  red[tid] = ss; __syncthreads();
  for (int s = 128; s > 0; s >>= 1) { if (tid < s) red[tid] += red[tid+s]; __syncthreads(); }
  const float S = red[0]; __syncthreads();

  // ---- target: 4 scatter bins convolved with 5x5 gaussian -> 6x6 window ----
  float k1d[5];
  {
    float ksum = 0.f;
#pragma unroll
    for (int i = 0; i < 5; ++i) { const float d = (float)(i-2); k1d[i] = expf(-d*d*1.125f); ksum += k1d[i]; }
#pragma unroll
    for (int i = 0; i < 5; ++i) k1d[i] /= ksum;
  }

  const float fy = floorf(ty), cy = ceilf(ty);
  const float fx = floorf(tx), cx = ceilf(tx);
  const float d0 = sqrtf(sqf(fy-ty+1e-6f) + sqf(fx-tx+1e-6f));
  const float d1 = sqrtf(sqf(fy-ty+1e-6f) + sqf(cx-tx+1e-6f));
  const float d2 = sqrtf(sqf(cy-ty+1e-6f) + sqf(fx-tx+1e-6f));
  const float d3 = sqrtf(sqf(cy-ty+1e-6f) + sqf(cx-tx+1e-6f));
  const float sd = fmaxf(d0+d1+d2+d3, 1e-12f);
  const float t0 = d0/sd, t1 = d1/sd, t2 = d2/sd, t3 = d3/sd;
  const int ify = (int)fy, ifx = (int)fx;
  const int ddy = (int)cy - ify, ddx = (int)cx - ifx;
  const float loc00 = t0 + (ddx==0?t1:0.f) + (ddy==0?t2:0.f) + ((ddy==0&&ddx==0)?t3:0.f);
  const float loc01 = (ddx==1?t1:0.f) + ((ddy==0&&ddx==1)?t3:0.f);
  const float loc10 = (ddy==1?t2:0.f) + ((ddy==1&&ddx==0)?t3:0.f);
  const float loc11 = ((ddy==1&&ddx==1)?t3:0.f);

  float val = 0.f;
  int by = 0, bx = 0;
  bool inb = false;
  if (tid < 36) {
    const int r = tid / 6, c = tid % 6;
    by = ify - 2 + r; bx = ifx - 2 + c;
    inb = (by >= 0 && by < HH && bx >= 0 && bx < WW);
    if (inb) {
      const float kr0 = (r <= 4) ? k1d[r]   : 0.f;
      const float kr1 = (r >= 1) ? k1d[r-1] : 0.f;
      const float kc0 = (c <= 4) ? k1d[c]   : 0.f;
      const float kc1 = (c >= 1) ? k1d[c-1] : 0.f;
      val = loc00*kr0*kc0 + loc01*kr0*kc1 + loc10*kr1*kc0 + loc11*kr1*kc1;
    }
  }

  red[tid] = inb ? val*val : 0.f; __syncthreads();
  for (int s = 128; s > 0; s >>= 1) { if (tid < s) red[tid] += red[tid+s]; __syncthreads(); }
  const float nrm2 = red[0]; __syncthreads();
  const float nrmc = fmaxf(sqrtf(nrm2), 1e-12f);
  const float tgtsq = nrm2 / (nrmc*nrmc);

  float dc = 0.f;
  if (tid < 36 && inb) {
    float predbin;
    if (dir == 0) {
      const int cbin = by*WW + bx;
      predbin = w00*r00[cbin] + w01*r01[cbin] + w10*r10[cbin] + w11*r11[cbin];
    } else {
      const float* slab = corr + bbase + (size_t)(by*WW + bx) * CC;
      predbin = w00*slab[o00] + w01*slab[o01] + w10*slab[o10] + w11*slab[o11];
    }
    dc = (val / nrmc) * predbin;
  }
  red[tid] = dc; __syncthreads();
  for (int s = 128; s > 0; s >>= 1) { if (tid < s) red[tid] += red[tid+s]; __syncthreads(); }

  if (tid == 0) partial[bidx] = S - 2.f*red[0] + tgtsq;
}

// Final reduce: per (dir,b) sum over n (adding streamed dir-1 S) -> sqrt ->
// mean over b -> add dirs.
__global__ void lpml_reduce(const float* __restrict__ partial,
                            const float* __restrict__ acc21,
                            float* __restrict__ out)
{
  __shared__ float sh[16];
  const int tid = threadIdx.x;
  if (tid < 16) {
    const int dir = tid >> 3, b = tid & 7;
    const float* p = partial + dir*(BB*NN) + b*NN;
    float s = 0.f;
    if (dir == 0) { for (int i = 0; i < NN; ++i) s += p[i]; }
    else          { for (int i = 0; i < NN; ++i) s += p[i] + acc21[b*NN + i]; }
    sh[tid] = sqrtf(s);
  }
  __syncthreads();
  if (tid == 0) {
    float l1 = 0.f, l2 = 0.f;
    for (int i = 0; i < BB; ++i) { l1 += sh[i]; l2 += sh[8+i]; }
    out[0] = l1/(float)BB + l2/(float)BB;
  }
}

extern "C" void kernel_launch(void* const* d_in, const int* in_sizes, int n_in,
                              void* d_out, int out_size, void* d_ws, size_t ws_size,
                              hipStream_t stream) {
  const float* corr = (const float*)d_in[0];  // (B,H,W,H,W) f32
  const float* kp   = (const float*)d_in[1];  // (B,N,2,2) f32
  float* partial = (float*)d_ws;                    // 2048 floats
  float* acc21   = (float*)d_ws + 2*BB*NN;          // 1024 floats

  hipLaunchKernelGGL(lpml_zero, dim3((BB*NN + 255)/256), dim3(256), 0, stream, acc21);
  hipLaunchKernelGGL(lpml_stream21, dim3(BB*HH*2), dim3(256), 0, stream,
                     corr, kp, acc21);
  hipLaunchKernelGGL(lpml_main, dim3(2*BB*NN), dim3(256), 0, stream,
                     corr, kp, partial);
  hipLaunchKernelGGL(lpml_reduce, dim3(1), dim3(64), 0, stream,
                     partial, acc21, (float*)d_out);
}